// Round 23
// baseline (141.324 us; speedup 1.0000x reference)
//
#include <hip/hip_runtime.h>
#include <hip/hip_bf16.h>
#include <math.h>

#define DIM 768
#define NHEADS 16
#define HD 48
#define NTOK 1568
#define BATCH 4
#define ROWS (BATCH * NTOK)     // 6272
#define QKV_COLS (3 * DIM)      // 2304

typedef __attribute__((ext_vector_type(8))) _Float16 f16x8;
typedef __attribute__((ext_vector_type(2))) __fp16 fp16v2;
typedef __attribute__((ext_vector_type(4))) float f32x4;

__device__ inline ushort f2h(float f) {
    union { _Float16 h; ushort u; } v; v.h = (_Float16)f; return v.u;
}
__device__ inline float h2f(ushort u) {
    union { _Float16 h; ushort u; } v; v.u = u; return (float)v.h;
}

// async global->LDS, 16B per lane; lds dest is wave-uniform base (+lane*16 by HW)
__device__ inline void gl16(const void* g, void* l) {
    __builtin_amdgcn_global_load_lds(
        (const __attribute__((address_space(1))) unsigned int*)g,
        (__attribute__((address_space(3))) unsigned int*)l, 16, 0, 0);
}

// bijective XCD swizzle (m204): contiguous wgid chunk per XCD
__device__ inline int xcd_swz(int orig, int nwg) {
    int xcd = orig & 7, idx = orig >> 3;
    int q = nwg >> 3, r = nwg & 7;
    return (xcd < r ? xcd * (q + 1) : r * (q + 1) + (xcd - r) * q) + idx;
}

// ---------------- fused prep: cast x + transpose Wq + transpose Wp -----------
#define NBA ((ROWS * DIM / 4 + 255) / 256)   // 4704
#define NBB ((QKV_COLS / 32) * (DIM / 32))   // 1728
#define NBC ((DIM / 32) * (DIM / 32))        // 576

__global__ __launch_bounds__(256) void prep_fused(
    const float* __restrict__ x, ushort* __restrict__ x_h,
    const float* __restrict__ Wq, ushort* __restrict__ WqT,
    const float* __restrict__ Wp, ushort* __restrict__ WpT) {
    const int bid = blockIdx.x, tid = threadIdx.x;
    if (bid < NBA) {
        int i = bid * 256 + tid;
        if (i < ROWS * DIM / 4) {
            float4 v = ((const float4*)x)[i];
            ushort4 o;
            o.x = f2h(v.x); o.y = f2h(v.y); o.z = f2h(v.z); o.w = f2h(v.w);
            ((ushort4*)x_h)[i] = o;
        }
        return;
    }
    __shared__ ushort tile[32][33];
    const int tx = tid & 31, ty = tid >> 5;   // 32x8
    const float* in; ushort* out; int R, C, bx, by;
    if (bid < NBA + NBB) {
        int b = bid - NBA;
        in = Wq; out = WqT; R = DIM; C = QKV_COLS;
        bx = b % (QKV_COLS / 32); by = b / (QKV_COLS / 32);
    } else {
        int b = bid - NBA - NBB;
        in = Wp; out = WpT; R = DIM; C = DIM;
        bx = b % (DIM / 32); by = b / (DIM / 32);
    }
    int c0 = bx * 32, r0 = by * 32;
#pragma unroll
    for (int k = 0; k < 4; ++k)
        tile[ty + 8 * k][tx] = f2h(in[(size_t)(r0 + ty + 8 * k) * C + c0 + tx]);
    __syncthreads();
#pragma unroll
    for (int k = 0; k < 4; ++k)
        out[(size_t)(c0 + ty + 8 * k) * R + r0 + tx] = tile[tx][ty + 8 * k];
}

// ---------------- fp16 MFMA GEMM: C[M][N] = A[M][K] * Bt[N][K]^T -------------
// Templated on BM (BN=128, BK=64). 1-D grid with bijective XCD swizzle (T1).
// Double-buffered gload_lds staging, depth-1 issue-early pipeline, ONE
// barrier per K-iter. SWAPPED mfma operands: lane holds m = lr (fixed),
// n = nb + g*4 + j (4 contiguous cols). If pos != null: RoPE in-epilogue.
// If Vt != null, blocks with n0 >= 1536 write V^T to vt[b][c][tok] instead.
// BM=64 for BOTH gemms: 1764/588 blocks -> better machine occupancy & less
// scheduler-round tail than BM=128's 882 blocks (r23 change for gemm1).
#define GBK 64

template <int BM>
__global__ __launch_bounds__(256) void gemm_f16(
    const ushort* __restrict__ A, const ushort* __restrict__ Bt,
    float* __restrict__ Cf, ushort* __restrict__ Cb, ushort* __restrict__ Vt,
    const float* __restrict__ bias, const int* __restrict__ pos,
    int M, int N, int K) {
    constexpr int MI = BM / 32;           // A m-frags per wave; A chunks/thread
    __shared__ ushort sA[2][BM * 64];
    __shared__ ushort sB[2][128 * 64];
    const int tid = threadIdx.x;
    const int wid = tid >> 6, lane = tid & 63;
    const int wm = wid >> 1, wn = wid & 1;          // 2x2 wave grid
    const int wgid = xcd_swz(blockIdx.x, gridDim.x);
    const int nbx = N / 128;
    const int m0 = (wgid / nbx) * BM, n0 = (wgid % nbx) * 128;
    const int lr = lane & 15, g = lane >> 4;

    auto STAGE = [&](int buf, int k0) {
#pragma unroll
        for (int i = 0; i < MI; ++i) {      // A: BM*8 chunks
            int c = tid + 256 * i;
            int row = c >> 3;
            int ch = (c & 7) ^ (row & 7);   // source pre-swizzle
            gl16(&A[(size_t)(m0 + row) * K + k0 + ch * 8], &sA[buf][(c & ~63) * 8]);
        }
#pragma unroll
        for (int i = 0; i < 4; ++i) {       // B: 1024 chunks
            int c = tid + 256 * i;
            int row = c >> 3;
            int ch = (c & 7) ^ (row & 7);
            gl16(&Bt[(size_t)(n0 + row) * K + k0 + ch * 8], &sB[buf][(c & ~63) * 8]);
        }
    };

    f32x4 acc[MI][4] = {};
    const int NK = K / GBK;
    STAGE(0, 0);
    for (int t = 0; t < NK; ++t) {
        const int cur = t & 1;
        asm volatile("s_waitcnt vmcnt(0)" ::: "memory");
        __builtin_amdgcn_s_barrier();
        if (t + 1 < NK) STAGE(cur ^ 1, (t + 1) * GBK);
#pragma unroll
        for (int k2 = 0; k2 < GBK; k2 += 32) {
            f16x8 af[MI], bg[4];
#pragma unroll
            for (int f = 0; f < MI; ++f) {
                int ra = wm * (BM / 2) + f * 16 + lr;
                int ba = (ra * 128 + k2 * 2 + g * 16) ^ ((ra & 7) << 4);
                af[f] = *(const f16x8*)((const char*)sA[cur] + ba);
            }
#pragma unroll
            for (int f = 0; f < 4; ++f) {
                int rb = wn * 64 + f * 16 + lr;
                int bb = (rb * 128 + k2 * 2 + g * 16) ^ ((rb & 7) << 4);
                bg[f] = *(const f16x8*)((const char*)sB[cur] + bb);
            }
#pragma unroll
            for (int mi = 0; mi < MI; ++mi)
#pragma unroll
                for (int ni = 0; ni < 4; ++ni)
                    acc[mi][ni] = __builtin_amdgcn_mfma_f32_16x16x32_f16(
                        bg[ni], af[mi], acc[mi][ni], 0, 0, 0);
        }
    }
    // epilogue: lane m = m0 + wm*(BM/2) + mi*16 + lr; n = nb + g*4 + j contiguous
    const bool vpath = (Vt != nullptr) && (n0 >= 2 * DIM);
    const float RINV = 0.31622776601683794f;   // 10000^(-1/8)
    const float RINV4 = 0.01f;                 // RINV^4
#pragma unroll
    for (int mi = 0; mi < MI; ++mi) {
        int m = m0 + wm * (BM / 2) + mi * 16 + lr;
#pragma unroll
        for (int ni = 0; ni < 4; ++ni) {
            int nb = n0 + wn * 64 + ni * 16 + g * 4;
            if (Cf) {
                float4 b4 = *(const float4*)&bias[nb];
                float4 o4;
                o4.x = acc[mi][ni][0] + b4.x;
                o4.y = acc[mi][ni][1] + b4.y;
                o4.z = acc[mi][ni][2] + b4.z;
                o4.w = acc[mi][ni][3] + b4.w;
                *(float4*)&Cf[(size_t)m * N + nb] = o4;
            } else if (vpath) {
                // vt[b][c][tok] = V^T; c = nb-1536+j, tok = m%NTOK
                int bb = m / NTOK, tok = m % NTOK;
#pragma unroll
                for (int j = 0; j < 4; ++j)
                    Vt[((size_t)bb * DIM + (nb - 2 * DIM + j)) * NTOK + tok] =
                        f2h(acc[mi][ni][j]);
            } else {
                float vv[4];
#pragma unroll
                for (int j = 0; j < 4; ++j) vv[j] = acc[mi][ni][j];
                if (pos) {   // RoPE on q/k cols (all Cb cols here are < 1536)
                    int tok = m % NTOK;
                    int axis = (nb >> 4) % 3;
                    float p = (float)pos[tok * 3 + axis];
                    float fj = (g & 1) ? RINV4 : 1.0f;
                    bool hi = (g & 2) != 0;
#pragma unroll
                    for (int j = 0; j < 4; ++j) {
                        float s, c; __sincosf(p * fj, &s, &c); fj *= RINV;
                        float part = __shfl_xor(vv[j], 32);
                        vv[j] = hi ? (vv[j] * c + part * s) : (vv[j] * c - part * s);
                    }
                }
                union { fp16v2 h; uint u; } c0, c1;
                c0.h = __builtin_amdgcn_cvt_pkrtz(vv[0], vv[1]);
                c1.h = __builtin_amdgcn_cvt_pkrtz(vv[2], vv[3]);
                uint2 uu; uu.x = c0.u; uu.y = c1.u;
                *(uint2*)&Cb[(size_t)m * N + nb] = uu;
            }
        }
    }
}

// ---------------- MFMA flash attention (fp16) --------------------------------
// Grid: (64 bh, 13 q-tiles), bh%8 = XCD. QBLK=128 (wave owns 32 q-rows).
// TRIPLE-buffered K/V via global_load_lds, depth-2 pipeline, ONE barrier/tile.
// Fixed-offset exp2 softmax (M2=14); -M2 in MFMA C-init; l via ones-row.
// NOTE: this structure (LDS 34.8KB / VGPR 56) is a measured local optimum —
// r16 (T15 2-deep), r18 (KVB=64), r19 (quad-buf epochs), r20 (KV-split) all
// regressed via occupancy/FETCH; do not grow per-wave or per-block state.
#define QBLK 128
#define KVB 32
#define NT (NTOK / KVB)   // 49
#define PP 40             // sP pitch

__global__ __launch_bounds__(256) void attn_mfma(const ushort* __restrict__ qkv,
                                                 const ushort* __restrict__ vt,
                                                 ushort* __restrict__ aout) {
    __shared__ ushort sK3[3][KVB * 64];   // [32][64] linear, 12 KB
    __shared__ ushort sV3[3][64 * 32];    // rows 0..47 V^T, 48 = ones; 12 KB
    __shared__ ushort sP[4][32 * PP];     // 10 KB
    const int tid = threadIdx.x, w = tid >> 6, lane = tid & 63;
    const int b = blockIdx.x >> 4, h = blockIdx.x & 15;
    const int q0 = blockIdx.y * QBLK;
    const size_t bbase = (size_t)b * NTOK * QKV_COLS;
    const size_t vbase = ((size_t)b * DIM + h * HD) * NTOK;
    const int lr = lane & 15, g = lane >> 4, lk = g << 3;
    const float qs = 0.14433756729740643f * 1.4426950408889634f;  // 1/sqrt(48)*log2e
    const float M2 = 14.0f;   // fixed exp2-domain offset (folded into C-init)

    // ones-row for l-accumulation (row 48 of all 3 V buffers)
    if (tid < 32) {
        sV3[0][48 * 32 + tid] = 0x3C00;   // 1.0 fp16
        sV3[1][48 * 32 + tid] = 0x3C00;
        sV3[2][48 * 32 + tid] = 0x3C00;
    }
    asm volatile("s_waitcnt lgkmcnt(0)" ::: "memory");

    // Q direct to registers, scaled by qs; cols >= 48 zero (nulls K garbage)
    f16x8 aq[2][2];
#pragma unroll
    for (int rb = 0; rb < 2; ++rb) {
        int qr = q0 + w * 32 + rb * 16 + lr;
        if (qr >= NTOK) qr = NTOK - 1;
        const ushort* qp = &qkv[bbase + (size_t)qr * QKV_COLS + h * HD];
        ushort r0[8], r1[8];
        *(ushort4*)&r0[0] = *(const ushort4*)&qp[lk];
        *(ushort4*)&r0[4] = *(const ushort4*)&qp[lk + 4];
        if (g < 2) {
            *(ushort4*)&r1[0] = *(const ushort4*)&qp[32 + lk];
            *(ushort4*)&r1[4] = *(const ushort4*)&qp[32 + lk + 4];
        } else {
#pragma unroll
            for (int e = 0; e < 8; ++e) r1[e] = 0;
        }
        f16x8 a0, a1;
#pragma unroll
        for (int e = 0; e < 8; ++e) {
            a0[e] = (_Float16)(h2f(r0[e]) * qs);
            a1[e] = (_Float16)(h2f(r1[e]) * qs);
        }
        aq[rb][0] = a0; aq[rb][1] = a1;
    }

    // stage K (256 chunks) + V (192 chunks) for tile kv0 into buffer buf
    auto STAGE = [&](int buf, int kv0) {
        {   // K: chunk c = tid; row = c>>3; source chunk swizzled
            int c = tid, row = c >> 3;
            int ch = (c & 7) ^ (row & 7);
            gl16(&qkv[bbase + (size_t)(kv0 + row) * QKV_COLS + DIM + h * HD + ch * 8],
                 &sK3[buf][(c & ~63) * 8]);
        }
        if (lane < 48) {   // V: wave w stages chunks w*48..w*48+47 (rows 0..47)
            int c = w * 48 + lane, d = c >> 2;
            int cc = (c & 3) ^ ((d >> 1) & 3);
            gl16(&vt[vbase + (size_t)d * NTOK + kv0 + cc * 8],
                 &sV3[buf][w * 384]);
        }
    };

    f32x4 o[2][4] = {};   // per rb: d 0..47 in [0..2]; [3][0] (g=0) = l

    STAGE(0, 0);
    STAGE(1, KVB);
    for (int t = 0; t < NT; ++t) {
        const int cur = t % 3;
        if (t + 1 < NT) asm volatile("s_waitcnt vmcnt(2)" ::: "memory");
        else            asm volatile("s_waitcnt vmcnt(0)" ::: "memory");
        __builtin_amdgcn_s_barrier();
        if (t + 2 < NT) STAGE((t + 2) % 3, (t + 2) * KVB);

        // S^T = K Q^T - M2: lane: q = rb*16+lr, keys = f*16 + 4g + j
        f16x8 bk[2][2];
#pragma unroll
        for (int f = 0; f < 2; ++f)
#pragma unroll
            for (int ks = 0; ks < 2; ++ks) {
                int row = f * 16 + lr;
                int byt = (row * 128 + ks * 64 + g * 16) ^ ((lr & 7) << 4);
                bk[f][ks] = *(const f16x8*)((const char*)sK3[cur] + byt);
            }
        f32x4 sacc[2][2] = {{{-M2, -M2, -M2, -M2}, {-M2, -M2, -M2, -M2}},
                            {{-M2, -M2, -M2, -M2}, {-M2, -M2, -M2, -M2}}};
        __builtin_amdgcn_s_setprio(1);
#pragma unroll
        for (int rb = 0; rb < 2; ++rb)
#pragma unroll
            for (int f = 0; f < 2; ++f) {
                sacc[rb][f] = __builtin_amdgcn_mfma_f32_16x16x32_f16(bk[f][0], aq[rb][0], sacc[rb][f], 0, 0, 0);
                sacc[rb][f] = __builtin_amdgcn_mfma_f32_16x16x32_f16(bk[f][1], aq[rb][1], sacc[rb][f], 0, 0, 0);
            }
        __builtin_amdgcn_s_setprio(0);

        // p = 2^(s2-M2); pack adjacent-key pairs (cvt_pkrtz) -> b64 stores
#pragma unroll
        for (int rb = 0; rb < 2; ++rb)
#pragma unroll
            for (int f = 0; f < 2; ++f) {
                float p[4];
#pragma unroll
                for (int j = 0; j < 4; ++j) {
                    float pv;
                    asm("v_exp_f32 %0, %1" : "=v"(pv) : "v"(sacc[rb][f][j]));
                    p[j] = pv;
                }
                union { fp16v2 h; uint u; } c0, c1;
                c0.h = __builtin_amdgcn_cvt_pkrtz(p[0], p[1]);
                c1.h = __builtin_amdgcn_cvt_pkrtz(p[2], p[3]);
                uint2 uu; uu.x = c0.u; uu.y = c1.u;
                *(uint2*)&sP[w][(rb * 16 + lr) * PP + f * 16 + 4 * g] = uu;
            }

        // PV (swapped): o^T = mfma(V^T, P): lane: q = lr, d = 16nf + 4g + j
        // nf=3 row 48 = ones -> accumulates l into o[rb][3] (g=0,j=0)
        f16x8 bv[4];
#pragma unroll
        for (int nf = 0; nf < 4; ++nf) {
            int row = nf * 16 + lr;
            int byt = (row * 64 + g * 16) ^ (((lr >> 1) & 3) << 4);
            bv[nf] = *(const f16x8*)((const char*)sV3[cur] + byt);
        }
        __builtin_amdgcn_s_setprio(1);
#pragma unroll
        for (int rb = 0; rb < 2; ++rb) {
            f16x8 pa = *(const f16x8*)&sP[w][(rb * 16 + lr) * PP + lk];
#pragma unroll
            for (int nf = 0; nf < 4; ++nf)
                o[rb][nf] = __builtin_amdgcn_mfma_f32_16x16x32_f16(bv[nf], pa, o[rb][nf], 0, 0, 0);
        }
        __builtin_amdgcn_s_setprio(0);
    }

    // epilogue: lane q = q0 + w*32 + rb*16 + lr; d = 16nf + 4g + j (contiguous)
#pragma unroll
    for (int rb = 0; rb < 2; ++rb) {
        float lv = __shfl(o[rb][3][0], lr, 64);   // l from g=0 lane of this q
        int qr = q0 + w * 32 + rb * 16 + lr;
        if (qr < NTOK) {
            float inv = 1.f / lv;
            size_t rbse = ((size_t)b * NTOK + qr) * DIM;
#pragma unroll
            for (int nf = 0; nf < 3; ++nf) {
                ushort4 h4;
#pragma unroll
                for (int j = 0; j < 4; ++j)
                    ((ushort*)&h4)[j] = f2h(o[rb][nf][j] * inv);
                *(ushort4*)&aout[rbse + h * HD + nf * 16 + 4 * g] = h4;
            }
        }
    }
}

// ---------------- launch ------------------------------------------------------
extern "C" void kernel_launch(void* const* d_in, const int* in_sizes, int n_in,
                              void* d_out, int out_size, void* d_ws, size_t ws_size,
                              hipStream_t stream) {
    const float* x   = (const float*)d_in[0];
    const int*   pos = (const int*)d_in[1];
    const float* Wq  = (const float*)d_in[2];
    const float* Wp  = (const float*)d_in[3];
    const float* bp  = (const float*)d_in[4];
    float* out = (float*)d_out;

    ushort* ws     = (ushort*)d_ws;
    ushort* x_h    = ws;                                    // 6272*768
    ushort* WqT    = x_h + (size_t)ROWS * DIM;              // 2304*768
    ushort* WpT    = WqT + (size_t)QKV_COLS * DIM;          // 768*768
    ushort* qkv_h  = WpT + (size_t)DIM * DIM;               // 6272*2304 (V third unused)
    ushort* aout   = qkv_h + (size_t)ROWS * QKV_COLS;       // 6272*768
    ushort* vt     = aout + (size_t)ROWS * DIM;             // 4*768*1568 (separate!)

    // fused prep: cast x + transpose Wq + transpose Wp in ONE dispatch
    prep_fused<<<NBA + NBB + NBC, 256, 0, stream>>>(x, x_h, Wq, WqT, Wp, WpT);

    // qkv = x @ W_qkv; q/k -> qkv_h (RoPE fused), v -> vt (V^T); XCD-swizzled
    // BM=64: 1764 blocks = 6.9/CU (was 882 = 3.44/CU -> 45%-full tail round)
    gemm_f16<64><<<(QKV_COLS / 128) * (ROWS / 64), 256, 0, stream>>>(
        x_h, WqT, nullptr, qkv_h, vt, nullptr, pos, ROWS, QKV_COLS, DIM);

    attn_mfma<<<dim3(BATCH * NHEADS, (NTOK + QBLK - 1) / QBLK), 256, 0, stream>>>(qkv_h, vt, aout);

    // out = aout @ WpT^T + b  (K=768, f32 out; BM=64; XCD-swizzled)
    gemm_f16<64><<<(DIM / 128) * (ROWS / 64), 256, 0, stream>>>(
        aout, WpT, out, nullptr, nullptr, bp, nullptr, ROWS, DIM, DIM);
}

// Round 24
// 135.249 us; speedup vs baseline: 1.0449x; 1.0449x over previous
//
#include <hip/hip_runtime.h>
#include <hip/hip_bf16.h>
#include <math.h>

#define DIM 768
#define NHEADS 16
#define HD 48
#define NTOK 1568
#define BATCH 4
#define ROWS (BATCH * NTOK)     // 6272
#define QKV_COLS (3 * DIM)      // 2304

typedef __attribute__((ext_vector_type(8))) _Float16 f16x8;
typedef __attribute__((ext_vector_type(2))) __fp16 fp16v2;
typedef __attribute__((ext_vector_type(4))) float f32x4;

__device__ inline ushort f2h(float f) {
    union { _Float16 h; ushort u; } v; v.h = (_Float16)f; return v.u;
}
__device__ inline float h2f(ushort u) {
    union { _Float16 h; ushort u; } v; v.u = u; return (float)v.h;
}

// async global->LDS, 16B per lane; lds dest is wave-uniform base (+lane*16 by HW)
__device__ inline void gl16(const void* g, void* l) {
    __builtin_amdgcn_global_load_lds(
        (const __attribute__((address_space(1))) unsigned int*)g,
        (__attribute__((address_space(3))) unsigned int*)l, 16, 0, 0);
}

// bijective XCD swizzle (m204): contiguous wgid chunk per XCD
__device__ inline int xcd_swz(int orig, int nwg) {
    int xcd = orig & 7, idx = orig >> 3;
    int q = nwg >> 3, r = nwg & 7;
    return (xcd < r ? xcd * (q + 1) : r * (q + 1) + (xcd - r) * q) + idx;
}

// ---------------- fused prep: cast x + transpose Wq + transpose Wp -----------
#define NBA ((ROWS * DIM / 4 + 255) / 256)   // 4704
#define NBB ((QKV_COLS / 32) * (DIM / 32))   // 1728
#define NBC ((DIM / 32) * (DIM / 32))        // 576

__global__ __launch_bounds__(256) void prep_fused(
    const float* __restrict__ x, ushort* __restrict__ x_h,
    const float* __restrict__ Wq, ushort* __restrict__ WqT,
    const float* __restrict__ Wp, ushort* __restrict__ WpT) {
    const int bid = blockIdx.x, tid = threadIdx.x;
    if (bid < NBA) {
        int i = bid * 256 + tid;
        if (i < ROWS * DIM / 4) {
            float4 v = ((const float4*)x)[i];
            ushort4 o;
            o.x = f2h(v.x); o.y = f2h(v.y); o.z = f2h(v.z); o.w = f2h(v.w);
            ((ushort4*)x_h)[i] = o;
        }
        return;
    }
    __shared__ ushort tile[32][33];
    const int tx = tid & 31, ty = tid >> 5;   // 32x8
    const float* in; ushort* out; int R, C, bx, by;
    if (bid < NBA + NBB) {
        int b = bid - NBA;
        in = Wq; out = WqT; R = DIM; C = QKV_COLS;
        bx = b % (QKV_COLS / 32); by = b / (QKV_COLS / 32);
    } else {
        int b = bid - NBA - NBB;
        in = Wp; out = WpT; R = DIM; C = DIM;
        bx = b % (DIM / 32); by = b / (DIM / 32);
    }
    int c0 = bx * 32, r0 = by * 32;
#pragma unroll
    for (int k = 0; k < 4; ++k)
        tile[ty + 8 * k][tx] = f2h(in[(size_t)(r0 + ty + 8 * k) * C + c0 + tx]);
    __syncthreads();
#pragma unroll
    for (int k = 0; k < 4; ++k)
        out[(size_t)(c0 + ty + 8 * k) * R + r0 + tx] = tile[tx][ty + 8 * k];
}

// ---------------- fp16 MFMA GEMM: C[M][N] = A[M][K] * Bt[N][K]^T -------------
// Templated on BM (BN=128, BK=64). 1-D grid with bijective XCD swizzle (T1).
// Double-buffered gload_lds staging, depth-1 issue-early pipeline, ONE
// barrier per K-iter. SWAPPED mfma operands: lane holds m = lr (fixed),
// n = nb + g*4 + j (4 contiguous cols). If pos != null: RoPE in-epilogue.
// If Vt != null, blocks with n0 >= 1536 write V^T to vt[b][c][tok] instead.
// BM split (r23 lesson): gemm1 BM=128 (BM=64 doubled B-staging cost, -6us);
// gemm2 BM=64 (K=768, 294 blocks at BM=128 was grid-starved).
#define GBK 64

template <int BM>
__global__ __launch_bounds__(256) void gemm_f16(
    const ushort* __restrict__ A, const ushort* __restrict__ Bt,
    float* __restrict__ Cf, ushort* __restrict__ Cb, ushort* __restrict__ Vt,
    const float* __restrict__ bias, const int* __restrict__ pos,
    int M, int N, int K) {
    constexpr int MI = BM / 32;           // A m-frags per wave; A chunks/thread
    __shared__ ushort sA[2][BM * 64];
    __shared__ ushort sB[2][128 * 64];
    const int tid = threadIdx.x;
    const int wid = tid >> 6, lane = tid & 63;
    const int wm = wid >> 1, wn = wid & 1;          // 2x2 wave grid
    const int wgid = xcd_swz(blockIdx.x, gridDim.x);
    const int nbx = N / 128;
    const int m0 = (wgid / nbx) * BM, n0 = (wgid % nbx) * 128;
    const int lr = lane & 15, g = lane >> 4;

    auto STAGE = [&](int buf, int k0) {
#pragma unroll
        for (int i = 0; i < MI; ++i) {      // A: BM*8 chunks
            int c = tid + 256 * i;
            int row = c >> 3;
            int ch = (c & 7) ^ (row & 7);   // source pre-swizzle
            gl16(&A[(size_t)(m0 + row) * K + k0 + ch * 8], &sA[buf][(c & ~63) * 8]);
        }
#pragma unroll
        for (int i = 0; i < 4; ++i) {       // B: 1024 chunks
            int c = tid + 256 * i;
            int row = c >> 3;
            int ch = (c & 7) ^ (row & 7);
            gl16(&Bt[(size_t)(n0 + row) * K + k0 + ch * 8], &sB[buf][(c & ~63) * 8]);
        }
    };

    f32x4 acc[MI][4] = {};
    const int NK = K / GBK;
    STAGE(0, 0);
    for (int t = 0; t < NK; ++t) {
        const int cur = t & 1;
        asm volatile("s_waitcnt vmcnt(0)" ::: "memory");
        __builtin_amdgcn_s_barrier();
        if (t + 1 < NK) STAGE(cur ^ 1, (t + 1) * GBK);
#pragma unroll
        for (int k2 = 0; k2 < GBK; k2 += 32) {
            f16x8 af[MI], bg[4];
#pragma unroll
            for (int f = 0; f < MI; ++f) {
                int ra = wm * (BM / 2) + f * 16 + lr;
                int ba = (ra * 128 + k2 * 2 + g * 16) ^ ((ra & 7) << 4);
                af[f] = *(const f16x8*)((const char*)sA[cur] + ba);
            }
#pragma unroll
            for (int f = 0; f < 4; ++f) {
                int rb = wn * 64 + f * 16 + lr;
                int bb = (rb * 128 + k2 * 2 + g * 16) ^ ((rb & 7) << 4);
                bg[f] = *(const f16x8*)((const char*)sB[cur] + bb);
            }
#pragma unroll
            for (int mi = 0; mi < MI; ++mi)
#pragma unroll
                for (int ni = 0; ni < 4; ++ni)
                    acc[mi][ni] = __builtin_amdgcn_mfma_f32_16x16x32_f16(
                        bg[ni], af[mi], acc[mi][ni], 0, 0, 0);
        }
    }
    // epilogue: lane m = m0 + wm*(BM/2) + mi*16 + lr; n = nb + g*4 + j contiguous
    const bool vpath = (Vt != nullptr) && (n0 >= 2 * DIM);
    const float RINV = 0.31622776601683794f;   // 10000^(-1/8)
    const float RINV4 = 0.01f;                 // RINV^4
#pragma unroll
    for (int mi = 0; mi < MI; ++mi) {
        int m = m0 + wm * (BM / 2) + mi * 16 + lr;
#pragma unroll
        for (int ni = 0; ni < 4; ++ni) {
            int nb = n0 + wn * 64 + ni * 16 + g * 4;
            if (Cf) {
                float4 b4 = *(const float4*)&bias[nb];
                float4 o4;
                o4.x = acc[mi][ni][0] + b4.x;
                o4.y = acc[mi][ni][1] + b4.y;
                o4.z = acc[mi][ni][2] + b4.z;
                o4.w = acc[mi][ni][3] + b4.w;
                *(float4*)&Cf[(size_t)m * N + nb] = o4;
            } else if (vpath) {
                // vt[b][c][tok] = V^T; c = nb-1536+j, tok = m%NTOK
                int bb = m / NTOK, tok = m % NTOK;
#pragma unroll
                for (int j = 0; j < 4; ++j)
                    Vt[((size_t)bb * DIM + (nb - 2 * DIM + j)) * NTOK + tok] =
                        f2h(acc[mi][ni][j]);
            } else {
                float vv[4];
#pragma unroll
                for (int j = 0; j < 4; ++j) vv[j] = acc[mi][ni][j];
                if (pos) {   // RoPE on q/k cols (all Cb cols here are < 1536)
                    int tok = m % NTOK;
                    int axis = (nb >> 4) % 3;
                    float p = (float)pos[tok * 3 + axis];
                    float fj = (g & 1) ? RINV4 : 1.0f;
                    bool hi = (g & 2) != 0;
#pragma unroll
                    for (int j = 0; j < 4; ++j) {
                        float s, c; __sincosf(p * fj, &s, &c); fj *= RINV;
                        float part = __shfl_xor(vv[j], 32);
                        vv[j] = hi ? (vv[j] * c + part * s) : (vv[j] * c - part * s);
                    }
                }
                union { fp16v2 h; uint u; } c0, c1;
                c0.h = __builtin_amdgcn_cvt_pkrtz(vv[0], vv[1]);
                c1.h = __builtin_amdgcn_cvt_pkrtz(vv[2], vv[3]);
                uint2 uu; uu.x = c0.u; uu.y = c1.u;
                *(uint2*)&Cb[(size_t)m * N + nb] = uu;
            }
        }
    }
}

// ---------------- MFMA flash attention (fp16) --------------------------------
// Grid: (64 bh, 13 q-tiles), bh%8 = XCD. QBLK=128 (wave owns 32 q-rows).
// TRIPLE-buffered K/V via global_load_lds, depth-2 pipeline, ONE barrier/tile.
// Fixed-offset exp2 softmax (M2=14); -M2 in MFMA C-init; l via ones-row.
// NOTE: this structure (LDS 34.8KB / VGPR 56) is a measured local optimum —
// r16 (T15 2-deep), r18 (KVB=64), r19 (quad-buf epochs), r20 (KV-split) all
// regressed via occupancy/FETCH; do not grow per-wave or per-block state.
#define QBLK 128
#define KVB 32
#define NT (NTOK / KVB)   // 49
#define PP 40             // sP pitch

__global__ __launch_bounds__(256) void attn_mfma(const ushort* __restrict__ qkv,
                                                 const ushort* __restrict__ vt,
                                                 ushort* __restrict__ aout) {
    __shared__ ushort sK3[3][KVB * 64];   // [32][64] linear, 12 KB
    __shared__ ushort sV3[3][64 * 32];    // rows 0..47 V^T, 48 = ones; 12 KB
    __shared__ ushort sP[4][32 * PP];     // 10 KB
    const int tid = threadIdx.x, w = tid >> 6, lane = tid & 63;
    const int b = blockIdx.x >> 4, h = blockIdx.x & 15;
    const int q0 = blockIdx.y * QBLK;
    const size_t bbase = (size_t)b * NTOK * QKV_COLS;
    const size_t vbase = ((size_t)b * DIM + h * HD) * NTOK;
    const int lr = lane & 15, g = lane >> 4, lk = g << 3;
    const float qs = 0.14433756729740643f * 1.4426950408889634f;  // 1/sqrt(48)*log2e
    const float M2 = 14.0f;   // fixed exp2-domain offset (folded into C-init)

    // ones-row for l-accumulation (row 48 of all 3 V buffers)
    if (tid < 32) {
        sV3[0][48 * 32 + tid] = 0x3C00;   // 1.0 fp16
        sV3[1][48 * 32 + tid] = 0x3C00;
        sV3[2][48 * 32 + tid] = 0x3C00;
    }
    asm volatile("s_waitcnt lgkmcnt(0)" ::: "memory");

    // Q direct to registers, scaled by qs; cols >= 48 zero (nulls K garbage)
    f16x8 aq[2][2];
#pragma unroll
    for (int rb = 0; rb < 2; ++rb) {
        int qr = q0 + w * 32 + rb * 16 + lr;
        if (qr >= NTOK) qr = NTOK - 1;
        const ushort* qp = &qkv[bbase + (size_t)qr * QKV_COLS + h * HD];
        ushort r0[8], r1[8];
        *(ushort4*)&r0[0] = *(const ushort4*)&qp[lk];
        *(ushort4*)&r0[4] = *(const ushort4*)&qp[lk + 4];
        if (g < 2) {
            *(ushort4*)&r1[0] = *(const ushort4*)&qp[32 + lk];
            *(ushort4*)&r1[4] = *(const ushort4*)&qp[32 + lk + 4];
        } else {
#pragma unroll
            for (int e = 0; e < 8; ++e) r1[e] = 0;
        }
        f16x8 a0, a1;
#pragma unroll
        for (int e = 0; e < 8; ++e) {
            a0[e] = (_Float16)(h2f(r0[e]) * qs);
            a1[e] = (_Float16)(h2f(r1[e]) * qs);
        }
        aq[rb][0] = a0; aq[rb][1] = a1;
    }

    // stage K (256 chunks) + V (192 chunks) for tile kv0 into buffer buf
    auto STAGE = [&](int buf, int kv0) {
        {   // K: chunk c = tid; row = c>>3; source chunk swizzled
            int c = tid, row = c >> 3;
            int ch = (c & 7) ^ (row & 7);
            gl16(&qkv[bbase + (size_t)(kv0 + row) * QKV_COLS + DIM + h * HD + ch * 8],
                 &sK3[buf][(c & ~63) * 8]);
        }
        if (lane < 48) {   // V: wave w stages chunks w*48..w*48+47 (rows 0..47)
            int c = w * 48 + lane, d = c >> 2;
            int cc = (c & 3) ^ ((d >> 1) & 3);
            gl16(&vt[vbase + (size_t)d * NTOK + kv0 + cc * 8],
                 &sV3[buf][w * 384]);
        }
    };

    f32x4 o[2][4] = {};   // per rb: d 0..47 in [0..2]; [3][0] (g=0) = l

    STAGE(0, 0);
    STAGE(1, KVB);
    for (int t = 0; t < NT; ++t) {
        const int cur = t % 3;
        if (t + 1 < NT) asm volatile("s_waitcnt vmcnt(2)" ::: "memory");
        else            asm volatile("s_waitcnt vmcnt(0)" ::: "memory");
        __builtin_amdgcn_s_barrier();
        if (t + 2 < NT) STAGE((t + 2) % 3, (t + 2) * KVB);

        // S^T = K Q^T - M2: lane: q = rb*16+lr, keys = f*16 + 4g + j
        f16x8 bk[2][2];
#pragma unroll
        for (int f = 0; f < 2; ++f)
#pragma unroll
            for (int ks = 0; ks < 2; ++ks) {
                int row = f * 16 + lr;
                int byt = (row * 128 + ks * 64 + g * 16) ^ ((lr & 7) << 4);
                bk[f][ks] = *(const f16x8*)((const char*)sK3[cur] + byt);
            }
        f32x4 sacc[2][2] = {{{-M2, -M2, -M2, -M2}, {-M2, -M2, -M2, -M2}},
                            {{-M2, -M2, -M2, -M2}, {-M2, -M2, -M2, -M2}}};
        __builtin_amdgcn_s_setprio(1);
#pragma unroll
        for (int rb = 0; rb < 2; ++rb)
#pragma unroll
            for (int f = 0; f < 2; ++f) {
                sacc[rb][f] = __builtin_amdgcn_mfma_f32_16x16x32_f16(bk[f][0], aq[rb][0], sacc[rb][f], 0, 0, 0);
                sacc[rb][f] = __builtin_amdgcn_mfma_f32_16x16x32_f16(bk[f][1], aq[rb][1], sacc[rb][f], 0, 0, 0);
            }
        __builtin_amdgcn_s_setprio(0);

        // p = 2^(s2-M2); pack adjacent-key pairs (cvt_pkrtz) -> b64 stores
#pragma unroll
        for (int rb = 0; rb < 2; ++rb)
#pragma unroll
            for (int f = 0; f < 2; ++f) {
                float p[4];
#pragma unroll
                for (int j = 0; j < 4; ++j) {
                    float pv;
                    asm("v_exp_f32 %0, %1" : "=v"(pv) : "v"(sacc[rb][f][j]));
                    p[j] = pv;
                }
                union { fp16v2 h; uint u; } c0, c1;
                c0.h = __builtin_amdgcn_cvt_pkrtz(p[0], p[1]);
                c1.h = __builtin_amdgcn_cvt_pkrtz(p[2], p[3]);
                uint2 uu; uu.x = c0.u; uu.y = c1.u;
                *(uint2*)&sP[w][(rb * 16 + lr) * PP + f * 16 + 4 * g] = uu;
            }

        // PV (swapped): o^T = mfma(V^T, P): lane: q = lr, d = 16nf + 4g + j
        // nf=3 row 48 = ones -> accumulates l into o[rb][3] (g=0,j=0)
        f16x8 bv[4];
#pragma unroll
        for (int nf = 0; nf < 4; ++nf) {
            int row = nf * 16 + lr;
            int byt = (row * 64 + g * 16) ^ (((lr >> 1) & 3) << 4);
            bv[nf] = *(const f16x8*)((const char*)sV3[cur] + byt);
        }
        __builtin_amdgcn_s_setprio(1);
#pragma unroll
        for (int rb = 0; rb < 2; ++rb) {
            f16x8 pa = *(const f16x8*)&sP[w][(rb * 16 + lr) * PP + lk];
#pragma unroll
            for (int nf = 0; nf < 4; ++nf)
                o[rb][nf] = __builtin_amdgcn_mfma_f32_16x16x32_f16(bv[nf], pa, o[rb][nf], 0, 0, 0);
        }
        __builtin_amdgcn_s_setprio(0);
    }

    // epilogue: lane q = q0 + w*32 + rb*16 + lr; d = 16nf + 4g + j (contiguous)
#pragma unroll
    for (int rb = 0; rb < 2; ++rb) {
        float lv = __shfl(o[rb][3][0], lr, 64);   // l from g=0 lane of this q
        int qr = q0 + w * 32 + rb * 16 + lr;
        if (qr < NTOK) {
            float inv = 1.f / lv;
            size_t rbse = ((size_t)b * NTOK + qr) * DIM;
#pragma unroll
            for (int nf = 0; nf < 3; ++nf) {
                ushort4 h4;
#pragma unroll
                for (int j = 0; j < 4; ++j)
                    ((ushort*)&h4)[j] = f2h(o[rb][nf][j] * inv);
                *(ushort4*)&aout[rbse + h * HD + nf * 16 + 4 * g] = h4;
            }
        }
    }
}

// ---------------- launch ------------------------------------------------------
extern "C" void kernel_launch(void* const* d_in, const int* in_sizes, int n_in,
                              void* d_out, int out_size, void* d_ws, size_t ws_size,
                              hipStream_t stream) {
    const float* x   = (const float*)d_in[0];
    const int*   pos = (const int*)d_in[1];
    const float* Wq  = (const float*)d_in[2];
    const float* Wp  = (const float*)d_in[3];
    const float* bp  = (const float*)d_in[4];
    float* out = (float*)d_out;

    ushort* ws     = (ushort*)d_ws;
    ushort* x_h    = ws;                                    // 6272*768
    ushort* WqT    = x_h + (size_t)ROWS * DIM;              // 2304*768
    ushort* WpT    = WqT + (size_t)QKV_COLS * DIM;          // 768*768
    ushort* qkv_h  = WpT + (size_t)DIM * DIM;               // 6272*2304 (V third unused)
    ushort* aout   = qkv_h + (size_t)ROWS * QKV_COLS;       // 6272*768
    ushort* vt     = aout + (size_t)ROWS * DIM;             // 4*768*1568 (separate!)

    // fused prep: cast x + transpose Wq + transpose Wp in ONE dispatch
    prep_fused<<<NBA + NBB + NBC, 256, 0, stream>>>(x, x_h, Wq, WqT, Wp, WpT);

    // qkv = x @ W_qkv; q/k -> qkv_h (RoPE fused), v -> vt (V^T); XCD-swizzled
    gemm_f16<128><<<(QKV_COLS / 128) * (ROWS / 128), 256, 0, stream>>>(
        x_h, WqT, nullptr, qkv_h, vt, nullptr, pos, ROWS, QKV_COLS, DIM);

    attn_mfma<<<dim3(BATCH * NHEADS, (NTOK + QBLK - 1) / QBLK), 256, 0, stream>>>(qkv_h, vt, aout);

    // out = aout @ WpT^T + b  (K=768, f32 out; BM=64; XCD-swizzled)
    gemm_f16<64><<<(DIM / 128) * (ROWS / 64), 256, 0, stream>>>(
        aout, WpT, out, nullptr, nullptr, bp, nullptr, ROWS, DIM, DIM);
}

// Round 26
// 134.403 us; speedup vs baseline: 1.0515x; 1.0063x over previous
//
#include <hip/hip_runtime.h>
#include <hip/hip_bf16.h>
#include <math.h>

#define DIM 768
#define NHEADS 16
#define HD 48
#define NTOK 1568
#define BATCH 4
#define ROWS (BATCH * NTOK)     // 6272
#define QKV_COLS (3 * DIM)      // 2304

typedef __attribute__((ext_vector_type(8))) _Float16 f16x8;
typedef __attribute__((ext_vector_type(2))) __fp16 fp16v2;
typedef __attribute__((ext_vector_type(4))) float f32x4;

__device__ inline ushort f2h(float f) {
    union { _Float16 h; ushort u; } v; v.h = (_Float16)f; return v.u;
}
__device__ inline float h2f(ushort u) {
    union { _Float16 h; ushort u; } v; v.u = u; return (float)v.h;
}

// async global->LDS, 16B per lane; lds dest is wave-uniform base (+lane*16 by HW)
__device__ inline void gl16(const void* g, void* l) {
    __builtin_amdgcn_global_load_lds(
        (const __attribute__((address_space(1))) unsigned int*)g,
        (__attribute__((address_space(3))) unsigned int*)l, 16, 0, 0);
}

// bijective XCD swizzle (m204): contiguous wgid chunk per XCD
__device__ inline int xcd_swz(int orig, int nwg) {
    int xcd = orig & 7, idx = orig >> 3;
    int q = nwg >> 3, r = nwg & 7;
    return (xcd < r ? xcd * (q + 1) : r * (q + 1) + (xcd - r) * q) + idx;
}

// ---------------- fused prep: cast x + transpose Wq + transpose Wp -----------
#define NBA ((ROWS * DIM / 4 + 255) / 256)   // 4704
#define NBB ((QKV_COLS / 32) * (DIM / 32))   // 1728
#define NBC ((DIM / 32) * (DIM / 32))        // 576

__global__ __launch_bounds__(256) void prep_fused(
    const float* __restrict__ x, ushort* __restrict__ x_h,
    const float* __restrict__ Wq, ushort* __restrict__ WqT,
    const float* __restrict__ Wp, ushort* __restrict__ WpT) {
    const int bid = blockIdx.x, tid = threadIdx.x;
    if (bid < NBA) {
        int i = bid * 256 + tid;
        if (i < ROWS * DIM / 4) {
            float4 v = ((const float4*)x)[i];
            ushort4 o;
            o.x = f2h(v.x); o.y = f2h(v.y); o.z = f2h(v.z); o.w = f2h(v.w);
            ((ushort4*)x_h)[i] = o;
        }
        return;
    }
    __shared__ ushort tile[32][33];
    const int tx = tid & 31, ty = tid >> 5;   // 32x8
    const float* in; ushort* out; int R, C, bx, by;
    if (bid < NBA + NBB) {
        int b = bid - NBA;
        in = Wq; out = WqT; R = DIM; C = QKV_COLS;
        bx = b % (QKV_COLS / 32); by = b / (QKV_COLS / 32);
    } else {
        int b = bid - NBA - NBB;
        in = Wp; out = WpT; R = DIM; C = DIM;
        bx = b % (DIM / 32); by = b / (DIM / 32);
    }
    int c0 = bx * 32, r0 = by * 32;
#pragma unroll
    for (int k = 0; k < 4; ++k)
        tile[ty + 8 * k][tx] = f2h(in[(size_t)(r0 + ty + 8 * k) * C + c0 + tx]);
    __syncthreads();
#pragma unroll
    for (int k = 0; k < 4; ++k)
        out[(size_t)(c0 + ty + 8 * k) * R + r0 + tx] = tile[tx][ty + 8 * k];
}

// ---------------- fp16 MFMA GEMM: C[M][N] = A[M][K] * Bt[N][K]^T -------------
// Templated on BM (BN=128, BK=64). 1-D grid with bijective XCD swizzle (T1).
// Double-buffered gload_lds staging, depth-1 issue-early pipeline, ONE
// barrier per K-iter. SWAPPED mfma operands: lane holds m = lr (fixed),
// n = nb + g*4 + j (4 contiguous cols). If pos != null: RoPE in-epilogue.
// If Vt != null, blocks with n0 >= 1536 write V^T to vt[b][c][tok] instead.
// BM split (r23 lesson): gemm1 BM=128 (BM=64 doubled B-staging cost, -6us);
// gemm2 BM=64 (K=768, 294 blocks at BM=128 was grid-starved).
#define GBK 64

template <int BM>
__global__ __launch_bounds__(256) void gemm_f16(
    const ushort* __restrict__ A, const ushort* __restrict__ Bt,
    float* __restrict__ Cf, ushort* __restrict__ Cb, ushort* __restrict__ Vt,
    const float* __restrict__ bias, const int* __restrict__ pos,
    int M, int N, int K) {
    constexpr int MI = BM / 32;           // A m-frags per wave; A chunks/thread
    __shared__ ushort sA[2][BM * 64];
    __shared__ ushort sB[2][128 * 64];
    const int tid = threadIdx.x;
    const int wid = tid >> 6, lane = tid & 63;
    const int wm = wid >> 1, wn = wid & 1;          // 2x2 wave grid
    const int wgid = xcd_swz(blockIdx.x, gridDim.x);
    const int nbx = N / 128;
    const int m0 = (wgid / nbx) * BM, n0 = (wgid % nbx) * 128;
    const int lr = lane & 15, g = lane >> 4;

    auto STAGE = [&](int buf, int k0) {
#pragma unroll
        for (int i = 0; i < MI; ++i) {      // A: BM*8 chunks
            int c = tid + 256 * i;
            int row = c >> 3;
            int ch = (c & 7) ^ (row & 7);   // source pre-swizzle
            gl16(&A[(size_t)(m0 + row) * K + k0 + ch * 8], &sA[buf][(c & ~63) * 8]);
        }
#pragma unroll
        for (int i = 0; i < 4; ++i) {       // B: 1024 chunks
            int c = tid + 256 * i;
            int row = c >> 3;
            int ch = (c & 7) ^ (row & 7);
            gl16(&Bt[(size_t)(n0 + row) * K + k0 + ch * 8], &sB[buf][(c & ~63) * 8]);
        }
    };

    f32x4 acc[MI][4] = {};
    const int NK = K / GBK;
    STAGE(0, 0);
    for (int t = 0; t < NK; ++t) {
        const int cur = t & 1;
        asm volatile("s_waitcnt vmcnt(0)" ::: "memory");
        __builtin_amdgcn_s_barrier();
        if (t + 1 < NK) STAGE(cur ^ 1, (t + 1) * GBK);
#pragma unroll
        for (int k2 = 0; k2 < GBK; k2 += 32) {
            f16x8 af[MI], bg[4];
#pragma unroll
            for (int f = 0; f < MI; ++f) {
                int ra = wm * (BM / 2) + f * 16 + lr;
                int ba = (ra * 128 + k2 * 2 + g * 16) ^ ((ra & 7) << 4);
                af[f] = *(const f16x8*)((const char*)sA[cur] + ba);
            }
#pragma unroll
            for (int f = 0; f < 4; ++f) {
                int rb = wn * 64 + f * 16 + lr;
                int bb = (rb * 128 + k2 * 2 + g * 16) ^ ((rb & 7) << 4);
                bg[f] = *(const f16x8*)((const char*)sB[cur] + bb);
            }
#pragma unroll
            for (int mi = 0; mi < MI; ++mi)
#pragma unroll
                for (int ni = 0; ni < 4; ++ni)
                    acc[mi][ni] = __builtin_amdgcn_mfma_f32_16x16x32_f16(
                        bg[ni], af[mi], acc[mi][ni], 0, 0, 0);
        }
    }
    // epilogue: lane m = m0 + wm*(BM/2) + mi*16 + lr; n = nb + g*4 + j contiguous
    const bool vpath = (Vt != nullptr) && (n0 >= 2 * DIM);
    const float RINV = 0.31622776601683794f;   // 10000^(-1/8)
    const float RINV4 = 0.01f;                 // RINV^4
#pragma unroll
    for (int mi = 0; mi < MI; ++mi) {
        int m = m0 + wm * (BM / 2) + mi * 16 + lr;
#pragma unroll
        for (int ni = 0; ni < 4; ++ni) {
            int nb = n0 + wn * 64 + ni * 16 + g * 4;
            if (Cf) {
                float4 b4 = *(const float4*)&bias[nb];
                float4 o4;
                o4.x = acc[mi][ni][0] + b4.x;
                o4.y = acc[mi][ni][1] + b4.y;
                o4.z = acc[mi][ni][2] + b4.z;
                o4.w = acc[mi][ni][3] + b4.w;
                *(float4*)&Cf[(size_t)m * N + nb] = o4;
            } else if (vpath) {
                // vt[b][c][tok] = V^T; c = nb-1536+j, tok = m%NTOK
                int bb = m / NTOK, tok = m % NTOK;
#pragma unroll
                for (int j = 0; j < 4; ++j)
                    Vt[((size_t)bb * DIM + (nb - 2 * DIM + j)) * NTOK + tok] =
                        f2h(acc[mi][ni][j]);
            } else {
                float vv[4];
#pragma unroll
                for (int j = 0; j < 4; ++j) vv[j] = acc[mi][ni][j];
                if (pos) {   // RoPE on q/k cols (all Cb cols here are < 1536)
                    int tok = m % NTOK;
                    int axis = (nb >> 4) % 3;
                    float p = (float)pos[tok * 3 + axis];
                    float fj = (g & 1) ? RINV4 : 1.0f;
                    bool hi = (g & 2) != 0;
#pragma unroll
                    for (int j = 0; j < 4; ++j) {
                        float s, c; __sincosf(p * fj, &s, &c); fj *= RINV;
                        float part = __shfl_xor(vv[j], 32);
                        vv[j] = hi ? (vv[j] * c + part * s) : (vv[j] * c - part * s);
                    }
                }
                union { fp16v2 h; uint u; } c0, c1;
                c0.h = __builtin_amdgcn_cvt_pkrtz(vv[0], vv[1]);
                c1.h = __builtin_amdgcn_cvt_pkrtz(vv[2], vv[3]);
                uint2 uu; uu.x = c0.u; uu.y = c1.u;
                *(uint2*)&Cb[(size_t)m * N + nb] = uu;
            }
        }
    }
}

// ---------------- MFMA flash attention (fp16) --------------------------------
// Grid: (64 bh, 13 q-tiles), bh%8 = XCD. QBLK=128 (wave owns 32 q-rows).
// TRIPLE-buffered K/V via global_load_lds, depth-2 pipeline, ONE barrier/tile.
// Fixed-offset exp2 softmax (M2=14); -M2 in MFMA C-init; l via ones-row.
// NOTE: this structure (LDS 34.8KB / VGPR 56) is a measured local optimum —
// r16 (T15 2-deep), r18 (KVB=64), r19 (quad-buf epochs), r20 (KV-split) and
// r25 (8-wave split: correctness fail) all failed to beat it; locked as final.
#define QBLK 128
#define KVB 32
#define NT (NTOK / KVB)   // 49
#define PP 40             // sP pitch

__global__ __launch_bounds__(256) void attn_mfma(const ushort* __restrict__ qkv,
                                                 const ushort* __restrict__ vt,
                                                 ushort* __restrict__ aout) {
    __shared__ ushort sK3[3][KVB * 64];   // [32][64] linear, 12 KB
    __shared__ ushort sV3[3][64 * 32];    // rows 0..47 V^T, 48 = ones; 12 KB
    __shared__ ushort sP[4][32 * PP];     // 10 KB
    const int tid = threadIdx.x, w = tid >> 6, lane = tid & 63;
    const int b = blockIdx.x >> 4, h = blockIdx.x & 15;
    const int q0 = blockIdx.y * QBLK;
    const size_t bbase = (size_t)b * NTOK * QKV_COLS;
    const size_t vbase = ((size_t)b * DIM + h * HD) * NTOK;
    const int lr = lane & 15, g = lane >> 4, lk = g << 3;
    const float qs = 0.14433756729740643f * 1.4426950408889634f;  // 1/sqrt(48)*log2e
    const float M2 = 14.0f;   // fixed exp2-domain offset (folded into C-init)

    // ones-row for l-accumulation (row 48 of all 3 V buffers)
    if (tid < 32) {
        sV3[0][48 * 32 + tid] = 0x3C00;   // 1.0 fp16
        sV3[1][48 * 32 + tid] = 0x3C00;
        sV3[2][48 * 32 + tid] = 0x3C00;
    }
    asm volatile("s_waitcnt lgkmcnt(0)" ::: "memory");

    // Q direct to registers, scaled by qs; cols >= 48 zero (nulls K garbage)
    f16x8 aq[2][2];
#pragma unroll
    for (int rb = 0; rb < 2; ++rb) {
        int qr = q0 + w * 32 + rb * 16 + lr;
        if (qr >= NTOK) qr = NTOK - 1;
        const ushort* qp = &qkv[bbase + (size_t)qr * QKV_COLS + h * HD];
        ushort r0[8], r1[8];
        *(ushort4*)&r0[0] = *(const ushort4*)&qp[lk];
        *(ushort4*)&r0[4] = *(const ushort4*)&qp[lk + 4];
        if (g < 2) {
            *(ushort4*)&r1[0] = *(const ushort4*)&qp[32 + lk];
            *(ushort4*)&r1[4] = *(const ushort4*)&qp[32 + lk + 4];
        } else {
#pragma unroll
            for (int e = 0; e < 8; ++e) r1[e] = 0;
        }
        f16x8 a0, a1;
#pragma unroll
        for (int e = 0; e < 8; ++e) {
            a0[e] = (_Float16)(h2f(r0[e]) * qs);
            a1[e] = (_Float16)(h2f(r1[e]) * qs);
        }
        aq[rb][0] = a0; aq[rb][1] = a1;
    }

    // stage K (256 chunks) + V (192 chunks) for tile kv0 into buffer buf
    auto STAGE = [&](int buf, int kv0) {
        {   // K: chunk c = tid; row = c>>3; source chunk swizzled
            int c = tid, row = c >> 3;
            int ch = (c & 7) ^ (row & 7);
            gl16(&qkv[bbase + (size_t)(kv0 + row) * QKV_COLS + DIM + h * HD + ch * 8],
                 &sK3[buf][(c & ~63) * 8]);
        }
        if (lane < 48) {   // V: wave w stages chunks w*48..w*48+47 (rows 0..47)
            int c = w * 48 + lane, d = c >> 2;
            int cc = (c & 3) ^ ((d >> 1) & 3);
            gl16(&vt[vbase + (size_t)d * NTOK + kv0 + cc * 8],
                 &sV3[buf][w * 384]);
        }
    };

    f32x4 o[2][4] = {};   // per rb: d 0..47 in [0..2]; [3][0] (g=0) = l

    STAGE(0, 0);
    STAGE(1, KVB);
    for (int t = 0; t < NT; ++t) {
        const int cur = t % 3;
        if (t + 1 < NT) asm volatile("s_waitcnt vmcnt(2)" ::: "memory");
        else            asm volatile("s_waitcnt vmcnt(0)" ::: "memory");
        __builtin_amdgcn_s_barrier();
        if (t + 2 < NT) STAGE((t + 2) % 3, (t + 2) * KVB);

        // S^T = K Q^T - M2: lane: q = rb*16+lr, keys = f*16 + 4g + j
        f16x8 bk[2][2];
#pragma unroll
        for (int f = 0; f < 2; ++f)
#pragma unroll
            for (int ks = 0; ks < 2; ++ks) {
                int row = f * 16 + lr;
                int byt = (row * 128 + ks * 64 + g * 16) ^ ((lr & 7) << 4);
                bk[f][ks] = *(const f16x8*)((const char*)sK3[cur] + byt);
            }
        f32x4 sacc[2][2] = {{{-M2, -M2, -M2, -M2}, {-M2, -M2, -M2, -M2}},
                            {{-M2, -M2, -M2, -M2}, {-M2, -M2, -M2, -M2}}};
        __builtin_amdgcn_s_setprio(1);
#pragma unroll
        for (int rb = 0; rb < 2; ++rb)
#pragma unroll
            for (int f = 0; f < 2; ++f) {
                sacc[rb][f] = __builtin_amdgcn_mfma_f32_16x16x32_f16(bk[f][0], aq[rb][0], sacc[rb][f], 0, 0, 0);
                sacc[rb][f] = __builtin_amdgcn_mfma_f32_16x16x32_f16(bk[f][1], aq[rb][1], sacc[rb][f], 0, 0, 0);
            }
        __builtin_amdgcn_s_setprio(0);

        // p = 2^(s2-M2); pack adjacent-key pairs (cvt_pkrtz) -> b64 stores
#pragma unroll
        for (int rb = 0; rb < 2; ++rb)
#pragma unroll
            for (int f = 0; f < 2; ++f) {
                float p[4];
#pragma unroll
                for (int j = 0; j < 4; ++j) {
                    float pv;
                    asm("v_exp_f32 %0, %1" : "=v"(pv) : "v"(sacc[rb][f][j]));
                    p[j] = pv;
                }
                union { fp16v2 h; uint u; } c0, c1;
                c0.h = __builtin_amdgcn_cvt_pkrtz(p[0], p[1]);
                c1.h = __builtin_amdgcn_cvt_pkrtz(p[2], p[3]);
                uint2 uu; uu.x = c0.u; uu.y = c1.u;
                *(uint2*)&sP[w][(rb * 16 + lr) * PP + f * 16 + 4 * g] = uu;
            }

        // PV (swapped): o^T = mfma(V^T, P): lane: q = lr, d = 16nf + 4g + j
        // nf=3 row 48 = ones -> accumulates l into o[rb][3] (g=0,j=0)
        f16x8 bv[4];
#pragma unroll
        for (int nf = 0; nf < 4; ++nf) {
            int row = nf * 16 + lr;
            int byt = (row * 64 + g * 16) ^ (((lr >> 1) & 3) << 4);
            bv[nf] = *(const f16x8*)((const char*)sV3[cur] + byt);
        }
        __builtin_amdgcn_s_setprio(1);
#pragma unroll
        for (int rb = 0; rb < 2; ++rb) {
            f16x8 pa = *(const f16x8*)&sP[w][(rb * 16 + lr) * PP + lk];
#pragma unroll
            for (int nf = 0; nf < 4; ++nf)
                o[rb][nf] = __builtin_amdgcn_mfma_f32_16x16x32_f16(bv[nf], pa, o[rb][nf], 0, 0, 0);
        }
        __builtin_amdgcn_s_setprio(0);
    }

    // epilogue: lane q = q0 + w*32 + rb*16 + lr; d = 16nf + 4g + j (contiguous)
#pragma unroll
    for (int rb = 0; rb < 2; ++rb) {
        float lv = __shfl(o[rb][3][0], lr, 64);   // l from g=0 lane of this q
        int qr = q0 + w * 32 + rb * 16 + lr;
        if (qr < NTOK) {
            float inv = 1.f / lv;
            size_t rbse = ((size_t)b * NTOK + qr) * DIM;
#pragma unroll
            for (int nf = 0; nf < 3; ++nf) {
                ushort4 h4;
#pragma unroll
                for (int j = 0; j < 4; ++j)
                    ((ushort*)&h4)[j] = f2h(o[rb][nf][j] * inv);
                *(ushort4*)&aout[rbse + h * HD + nf * 16 + 4 * g] = h4;
            }
        }
    }
}

// ---------------- launch ------------------------------------------------------
extern "C" void kernel_launch(void* const* d_in, const int* in_sizes, int n_in,
                              void* d_out, int out_size, void* d_ws, size_t ws_size,
                              hipStream_t stream) {
    const float* x   = (const float*)d_in[0];
    const int*   pos = (const int*)d_in[1];
    const float* Wq  = (const float*)d_in[2];
    const float* Wp  = (const float*)d_in[3];
    const float* bp  = (const float*)d_in[4];
    float* out = (float*)d_out;

    ushort* ws     = (ushort*)d_ws;
    ushort* x_h    = ws;                                    // 6272*768
    ushort* WqT    = x_h + (size_t)ROWS * DIM;              // 2304*768
    ushort* WpT    = WqT + (size_t)QKV_COLS * DIM;          // 768*768
    ushort* qkv_h  = WpT + (size_t)DIM * DIM;               // 6272*2304 (V third unused)
    ushort* aout   = qkv_h + (size_t)ROWS * QKV_COLS;       // 6272*768
    ushort* vt     = aout + (size_t)ROWS * DIM;             // 4*768*1568 (separate!)

    // fused prep: cast x + transpose Wq + transpose Wp in ONE dispatch
    prep_fused<<<NBA + NBB + NBC, 256, 0, stream>>>(x, x_h, Wq, WqT, Wp, WpT);

    // qkv = x @ W_qkv; q/k -> qkv_h (RoPE fused), v -> vt (V^T); XCD-swizzled
    gemm_f16<128><<<(QKV_COLS / 128) * (ROWS / 128), 256, 0, stream>>>(
        x_h, WqT, nullptr, qkv_h, vt, nullptr, pos, ROWS, QKV_COLS, DIM);

    attn_mfma<<<dim3(BATCH * NHEADS, (NTOK + QBLK - 1) / QBLK), 256, 0, stream>>>(qkv_h, vt, aout);

    // out = aout @ WpT^T + b  (K=768, f32 out; BM=64; XCD-swizzled)
    gemm_f16<64><<<(DIM / 128) * (ROWS / 64), 256, 0, stream>>>(
        aout, WpT, out, nullptr, nullptr, bp, nullptr, ROWS, DIM, DIM);
}